// Round 2
// 833.828 us; speedup vs baseline: 1.0802x; 1.0802x over previous
//
#include <hip/hip_runtime.h>
#include <cstdint>

// Problem constants (fixed by setup_inputs: data (96,256,64,64) fp32, p=2)
#define NB 8            // batches (96/12)
#define NC 256          // channels
#define FH 64           // face H=W
#define OW 68           // padded width/height (64 + 2*2)
#define IMG_IN 4096     // 64*64
#define IMG_OUT 4624    // 68*68
#define N_IMG 24576     // 96*256 channel-images
#define Q_PER_IMG 1156  // 68*68 / 4 float4 per output image (68 % 4 == 0: no row-crossing)

// Native clang vector type — required by __builtin_nontemporal_store
// (HIP's float4 is a class and is rejected by the builtin).
typedef float f32x4 __attribute__((ext_vector_type(4)));

// Neighbor-face tables, indexed by face id fi in [0,12).
// fi 0-3: north (_pn), 4-7: equator (_pe), 8-11: south (_ps).
// For equator faces, TL corner is _tl(t,lft) and BR corner is _br(b,rgt),
// so tTL/tBR entries for 4-7 are unused.
__device__ const int c_tT[12]  = {1,2,3,0,  0,1,2,3,  5,6,7,4};
__device__ const int c_tTL[12] = {2,3,0,1,  0,0,0,0,  0,1,2,3};
__device__ const int c_tL[12]  = {3,0,1,2,  3,0,1,2,  4,5,6,7};
__device__ const int c_tBL[12] = {3,0,1,2,  7,4,5,6,  11,8,9,10};
__device__ const int c_tB[12]  = {4,5,6,7,  11,8,9,10, 11,8,9,10};
__device__ const int c_tBR[12] = {8,9,10,11, 0,0,0,0,  10,11,8,9};
__device__ const int c_tR[12]  = {5,6,7,4,  8,9,10,11, 9,10,11,8};
__device__ const int c_tTR[12] = {1,2,3,0,  5,6,7,4,  9,10,11,8};

// ---------------------------------------------------------------------------
// Halo math (verified in previous session, absmax 0.0). Derived from the JAX
// reference:
//   rot90(m,1)[i,j]  = m[j, 63-i]
//   rot90(m,-1)[i,j] = m[63-j, i]
//   rot90(m,2)[i,j]  = m[63-i, 63-j]
// p=2 corner blends from _tl/_br specialized below.
// In the fused kernel bb/ch/fi are wave-uniform, so the table loads become
// scalar loads and the region branches are mostly uniform per wave.
// ---------------------------------------------------------------------------
__device__ __forceinline__ float halo_value(const float* __restrict__ in,
                                            int bb, int ch, int fi,
                                            int oy, int ox) {
    auto ld = [&](int face, int sy, int sx) -> float {
        return in[(((bb * 12 + face) * NC + ch) * IMG_IN) + sy * 64 + sx];
    };

    const int y = oy - 2;
    const int x = ox - 2;
    const int rx = (ox < 2) ? 0 : (ox < 66 ? 1 : 2);
    const int ry = (oy < 2) ? 0 : (oy < 66 ? 1 : 2);
    const int ft = fi >> 2;   // 0=north, 1=equator, 2=south

    float v = 0.0f;

    if (ft == 0) {                              // _pn
        if (ry == 0) {
            if (rx == 1)      v = ld(c_tT[fi], x, 1 - oy);              // rot90(t,1)[-2:,:]
            else if (rx == 0) v = ld(c_tTL[fi], 1 - oy, 1 - ox);        // rot90(tl,2)[-2:,-2:]
            else              v = ld(c_tTR[fi], 62 + oy, x - 64);       // tr[-2:,:2]
        } else if (ry == 1) {
            if (rx == 0)      v = ld(c_tL[fi], 1 - ox, y);              // rot90(lft,-1)[:,-2:]
            else              v = ld(c_tR[fi], y, x - 64);              // rgt[:,:2]
        } else {
            if (rx == 1)      v = ld(c_tB[fi], y - 64, x);              // b[:2,:]
            else if (rx == 0) v = ld(c_tBL[fi], y - 64, 62 + ox);       // bl[:2,-2:]
            else              v = ld(c_tBR[fi], y - 64, x - 64);        // br[:2,:2]
        }
    } else if (ft == 1) {                       // _pe
        if (ry == 0) {
            if (rx == 1)      v = ld(c_tT[fi], 62 + oy, x);             // t[-2:,:]
            else if (rx == 2) v = ld(c_tTR[fi], 62 + oy, x - 64);       // tr[-2:,:2]
            else {                                                      // _tl(t,lft)[oy][ox]
                int r = oy, c = ox;
                if (c > r)      v = ld(c_tT[fi], 62 + r, c - r - 1);
                else if (r > c) v = ld(c_tL[fi], r - c - 1, 62 + c);
                else            v = 0.5f * (ld(c_tT[fi], 62 + r, 0) +
                                            ld(c_tL[fi], 0, 62 + r));
            }
        } else if (ry == 1) {
            if (rx == 0)      v = ld(c_tL[fi], y, 62 + ox);             // lft[:,-2:]
            else              v = ld(c_tR[fi], y, x - 64);              // rgt[:,:2]
        } else {
            if (rx == 1)      v = ld(c_tB[fi], y - 64, x);              // b[:2,:]
            else if (rx == 0) v = ld(c_tBL[fi], y - 64, 62 + ox);       // bl[:2,-2:]
            else {                                                      // _br(b,rgt)[y-64][x-64]
                int r = y - 64, c = x - 64;
                if (r > c)      v = ld(c_tB[fi], r, 64 - r + c);
                else if (c > r) v = ld(c_tR[fi], 64 - c + r, c);
                else            v = 0.5f * (ld(c_tB[fi], r, 63) +
                                            ld(c_tR[fi], 63, r));
            }
        }
    } else {                                    // _ps
        if (ry == 0) {
            if (rx == 1)      v = ld(c_tT[fi], 62 + oy, x);             // t[-2:,:]
            else if (rx == 0) v = ld(c_tTL[fi], 62 + oy, 62 + ox);      // tl[-2:,-2:]
            else              v = ld(c_tTR[fi], 62 + oy, x - 64);       // tr[-2:,:2]
        } else if (ry == 1) {
            if (rx == 0)      v = ld(c_tL[fi], y, 62 + ox);             // lft[:,-2:]
            else              v = ld(c_tR[fi], 127 - x, y);             // rot90(rgt,-1)[:,:2]
        } else {
            if (rx == 1)      v = ld(c_tB[fi], x, 127 - y);             // rot90(b,1)[:2,:]
            else if (rx == 0) v = ld(c_tBL[fi], y - 64, 62 + ox);       // bl[:2,-2:]
            else              v = ld(c_tBR[fi], 127 - y, 127 - x);      // rot90(br,2)[:2,:2]
        }
    }
    return v;
}

// ---------------------------------------------------------------------------
// Fused kernel: one block per channel-image (24576 blocks x 256 threads).
// Output decomposed into flat float4s: 68*68/4 = 1156 per image, 17 per row
// (68 % 4 == 0 so a float4 never crosses a row), image base is 16B-aligned
// (4624*4 B = 18496 ≡ 0 mod 16) => every store is an aligned, coalesced
// global_store_dwordx4 and every output byte is written exactly once.
// Interior lanes: two aligned float2 loads (input offset ≡ 2 mod 4).
// Edge/halo lanes (11.4% of elements): scalar halo_value path.
// fi/bb/ch are uniform per block => scalar table loads, uniform branches.
// ---------------------------------------------------------------------------
__global__ __launch_bounds__(256) void fused_pad(const float* __restrict__ in,
                                                 float* __restrict__ out) {
    const int img = blockIdx.x;          // 0..24575  (= nf*256 + ch)
    const int nf  = img >> 8;
    const int ch  = img & 255;
    const int bb  = nf / 12;
    const int fi  = nf - bb * 12;
    const float* __restrict__ base = in + (size_t)img * IMG_IN;
    f32x4* __restrict__ obase =
        reinterpret_cast<f32x4*>(out + (size_t)img * IMG_OUT);
    const int tid = threadIdx.x;

    auto process = [&](int q) {
        const int oy  = q / 17;                 // magic-mul, cheap
        const int ox0 = (q - oy * 17) << 2;     // 0,4,...,64
        f32x4 v;
        if (oy >= 2 && oy < 66 && ox0 >= 4 && ox0 < 64) {
            // fully-interior float4: elements ox0..ox0+3 all map to input.
            // input offset (oy-2)*64 + (ox0-2) is ≡ 2 mod 4 -> two float2s.
            const float* s = base + (oy - 2) * 64 + (ox0 - 2);
            const float2 a = *reinterpret_cast<const float2*>(s);
            const float2 b = *reinterpret_cast<const float2*>(s + 2);
            v.x = a.x; v.y = a.y; v.z = b.x; v.w = b.y;
        } else {
#pragma unroll
            for (int k = 0; k < 4; ++k) {
                const int ox = ox0 + k;
                float e;
                if (oy >= 2 && oy < 66 && ox >= 2 && ox < 66)
                    e = base[(oy - 2) * 64 + (ox - 2)];
                else
                    e = halo_value(in, bb, ch, fi, oy, ox);
                v[k] = e;
            }
        }
        // Output is never re-read: stream it, keep L2 for input edge lines.
        __builtin_nontemporal_store(v, obase + q);
    };

#pragma unroll
    for (int i = 0; i < 4; ++i)                 // q = tid .. tid+768 < 1024
        process(tid + i * 256);
    if (tid < Q_PER_IMG - 1024)                 // remaining 132 float4s
        process(tid + 1024);
}

extern "C" void kernel_launch(void* const* d_in, const int* in_sizes, int n_in,
                              void* d_out, int out_size, void* d_ws, size_t ws_size,
                              hipStream_t stream) {
    const float* in = (const float*)d_in[0];
    float* out = (float*)d_out;
    fused_pad<<<N_IMG, 256, 0, stream>>>(in, out);
}